// Round 5
// baseline (163.714 us; speedup 1.0000x reference)
//
#include <hip/hip_runtime.h>
#include <math.h>

namespace {

constexpr int   kB     = 16;
constexpr int   kA     = 65536;
constexpr int   kM     = 32;
constexpr int   kC     = 20;
constexpr float kImg   = 600.0f;
constexpr int   kBlock = 256;
constexpr int   kApT   = 2;                       // anchors per thread, kernel 1
constexpr int   kGrid1 = kA / (kBlock * kApT);    // 128
constexpr int   kGrid2 = kA / kBlock;             // 256
constexpr int   kNB1   = kGrid1 * kB;             // 2048
constexpr int   kNB2   = kGrid2 * kB;             // 4096

// d_ws layout (all within harness-provided scratch):
//   [0)            int   gcode[kB*kA]      (4 MB)
//   [codeEnd)      float p1[kNB1*2]        loc,npos per block
//   [..)           float p2[kNB2]          cls per block
constexpr size_t kCodeFloats = (size_t)kB * kA;   // ints, same 4B

__device__ __forceinline__ float smooth_l1(float d) {
    float ad = fabsf(d);
    return ad < 1.0f ? 0.5f * d * d : ad - 0.5f;
}

// ---------------- Kernel 1: IoU argmax + loc loss + code emit ----------------
__global__ __launch_bounds__(kBlock) void iou_kernel(
    const float* __restrict__ loc_preds,   // [B, A, 4]
    const float* __restrict__ iou_boxes,   // [A, 4] xywh
    const float* __restrict__ targets,     // [B*M, 6]
    int*   __restrict__ gcode,             // [B*A]
    float* __restrict__ p1)                // [kNB1][2] loc,npos
{
    __shared__ float4 sbox[kM];
    __shared__ float4 sxywh[kM];
    __shared__ float  sarea[kM];
    __shared__ int    slab[kM];
    __shared__ float  sred[2][kBlock / 64];

    const int b  = blockIdx.y;
    const int ab = blockIdx.x * (kBlock * kApT);

    if (threadIdx.x < kM) {
        const float* t = targets + ((size_t)(b * kM + threadIdx.x)) * 6;
        float cx = t[2] * kImg, cy = t[3] * kImg;
        float w  = t[4] * kImg, h  = t[5] * kImg;
        float x1  = cx - w * 0.5f,        y1  = cy - h * 0.5f;
        float x2p = cx + w * 0.5f + 1.0f, y2p = cy + h * 0.5f + 1.0f;
        sbox[threadIdx.x]  = make_float4(x1, y1, x2p, y2p);
        sxywh[threadIdx.x] = make_float4(cx, cy, w, h);
        sarea[threadIdx.x] = (x2p - x1) * (y2p - y1);
        slab[threadIdx.x]  = (int)t[1];
    }

    // Up-front loads: 4 independent float4 per thread.
    float4 an[kApT], lp[kApT];
    int    aidx[kApT];
#pragma unroll
    for (int k = 0; k < kApT; ++k) {
        aidx[k] = ab + k * kBlock + threadIdx.x;
        an[k] = *(const float4*)(iou_boxes + (size_t)aidx[k] * 4);
        lp[k] = *(const float4*)(loc_preds + ((size_t)b * kA + aidx[k]) * 4);
    }
    __syncthreads();

    float ax1[kApT], ay1[kApT], ax2p[kApT], ay2p[kApT], aarea[kApT];
#pragma unroll
    for (int k = 0; k < kApT; ++k) {
        ax1[k]  = an[k].x - an[k].z * 0.5f;
        ay1[k]  = an[k].y - an[k].w * 0.5f;
        ax2p[k] = an[k].x + an[k].z * 0.5f + 1.0f;
        ay2p[k] = an[k].y + an[k].w * 0.5f + 1.0f;
        aarea[k] = (ax2p[k] - ax1[k]) * (ay2p[k] - ay1[k]);
    }

    float best[kApT] = {-1.0f, -1.0f};
    int   mid[kApT]  = {0, 0};
#pragma unroll
    for (int m = 0; m < kM; ++m) {
        const float4 q  = sbox[m];
        const float  ta = sarea[m];
#pragma unroll
        for (int k = 0; k < kApT; ++k) {
            float lx = fmaxf(ax1[k],  q.x);
            float ly = fmaxf(ay1[k],  q.y);
            float rx = fminf(ax2p[k], q.z);
            float ry = fminf(ay2p[k], q.w);
            float w  = fmaxf(rx - lx, 0.0f);
            float h  = fmaxf(ry - ly, 0.0f);
            float inter = w * h;
            float uni   = aarea[k] + ta - inter;
            float iou   = inter * __builtin_amdgcn_rcpf(uni);
            if (iou > best[k]) { best[k] = iou; mid[k] = m; }
        }
    }

    float loc_sum = 0.0f, npos = 0.0f;
#pragma unroll
    for (int k = 0; k < kApT; ++k) {
        const bool pos = best[k] >= 0.5f;
        const bool ign = (best[k] > 0.4f) && !pos;
        if (pos) {
            npos += 1.0f;
            float4 mb = sxywh[mid[k]];
            float ltx = (mb.x - an[k].x) * __builtin_amdgcn_rcpf(an[k].z);
            float lty = (mb.y - an[k].y) * __builtin_amdgcn_rcpf(an[k].w);
            float ltw = __logf(mb.z * __builtin_amdgcn_rcpf(an[k].z));
            float lth = __logf(mb.w * __builtin_amdgcn_rcpf(an[k].w));
            loc_sum += smooth_l1(lp[k].x - ltx) + smooth_l1(lp[k].y - lty) +
                       smooth_l1(lp[k].z - ltw) + smooth_l1(lp[k].w - lth);
        }
        gcode[(size_t)b * kA + aidx[k]] = ign ? -1 : (pos ? slab[mid[k]] + 1 : 0);
    }

#pragma unroll
    for (int off = 32; off > 0; off >>= 1) {
        loc_sum += __shfl_down(loc_sum, off);
        npos    += __shfl_down(npos, off);
    }
    const int lane = threadIdx.x & 63;
    const int wid  = threadIdx.x >> 6;
    if (lane == 0) { sred[0][wid] = loc_sum; sred[1][wid] = npos; }
    __syncthreads();
    if (threadIdx.x == 0) {
        float l = 0.0f, n = 0.0f;
#pragma unroll
        for (int i = 0; i < kBlock / 64; ++i) { l += sred[0][i]; n += sred[1][i]; }
        const int bid = blockIdx.y * gridDim.x + blockIdx.x;
        p1[2 * bid + 0] = l;
        p1[2 * bid + 1] = n;
    }
}

// ---------------- Kernel 2: focal loss, pure stream, no barriers ----------------
__global__ __launch_bounds__(kBlock) void focal_kernel(
    const float* __restrict__ cls_preds,   // [B, A, C]
    const int*   __restrict__ gcode,       // [B*A]
    float* __restrict__ p2)                // [kNB2] cls per block
{
    __shared__ float sred[kBlock / 64];

    const int b  = blockIdx.y;
    const int ab = blockIdx.x * kBlock;
    const float* cp0 = cls_preds + ((size_t)b * kA + ab) * kC;
    const int*   gc0 = gcode + (size_t)b * kA + ab;

    float cls_sum = 0.0f;
#pragma unroll
    for (int i = 0; i < kC / 4; ++i) {
        const int f  = i * kBlock + threadIdx.x;   // float4 index in block slab
        const int al = f / 5;                      // anchor local [0,256)
        const int cb = (f - al * 5) * 4;           // class base 0,4,8,12,16
        const float4 v = *(const float4*)(cp0 + (size_t)f * 4);
        const int code = gc0[al];                  // 5 lanes share a dword (L1)
        const float live = (code >= 0) ? 1.0f : 0.0f;
        float xs[4] = {v.x, v.y, v.z, v.w};
        float csum = 0.0f;
#pragma unroll
        for (int j = 0; j < 4; ++j) {
            float x = xs[j];
            bool  t = (cb + j + 1) == code;
            float z = t ? -x : x;
            float e = __expf(-fabsf(z));                   // exp(-|z|)
            float r = __builtin_amdgcn_rcpf(1.0f + e);
            float sig = (z >= 0.0f) ? r : e * r;           // sigmoid(z) = 1-pt
            float sp  = __logf(1.0f + e) + fmaxf(z, 0.0f); // softplus(z) = bce
            float alw = t ? 0.25f : 0.75f;
            csum += alw * sig * sig * sp;
        }
        cls_sum += live * csum;
    }

#pragma unroll
    for (int off = 32; off > 0; off >>= 1)
        cls_sum += __shfl_down(cls_sum, off);
    const int lane = threadIdx.x & 63;
    const int wid  = threadIdx.x >> 6;
    if (lane == 0) sred[wid] = cls_sum;
    __syncthreads();
    if (threadIdx.x == 0) {
        float c = 0.0f;
#pragma unroll
        for (int i = 0; i < kBlock / 64; ++i) c += sred[i];
        p2[blockIdx.y * gridDim.x + blockIdx.x] = c;
    }
}

// ---------------- Final reduction ----------------
__global__ __launch_bounds__(1024) void retina_final(
    const float* __restrict__ p1, const float* __restrict__ p2,
    float* __restrict__ out)
{
    __shared__ float s[3][16];
    float l = 0.0f, c = 0.0f, n = 0.0f;
    for (int i = threadIdx.x; i < kNB1; i += 1024) {
        l += p1[2 * i + 0];
        n += p1[2 * i + 1];
    }
    for (int i = threadIdx.x; i < kNB2; i += 1024)
        c += p2[i];
#pragma unroll
    for (int off = 32; off > 0; off >>= 1) {
        l += __shfl_down(l, off);
        c += __shfl_down(c, off);
        n += __shfl_down(n, off);
    }
    const int lane = threadIdx.x & 63;
    const int wid  = threadIdx.x >> 6;
    if (lane == 0) { s[0][wid] = l; s[1][wid] = c; s[2][wid] = n; }
    __syncthreads();
    if (threadIdx.x == 0) {
        float L = 0.0f, C = 0.0f, N = 0.0f;
#pragma unroll
        for (int i = 0; i < 16; ++i) { L += s[0][i]; C += s[1][i]; N += s[2][i]; }
        float np  = fmaxf(1.0f, N);
        float inv = 1.0f / np;
        out[0] = (L + C) * inv;
        out[1] = L * inv;
        out[2] = C * inv;
    }
}

}  // namespace

extern "C" void kernel_launch(void* const* d_in, const int* in_sizes, int n_in,
                              void* d_out, int out_size, void* d_ws, size_t ws_size,
                              hipStream_t stream) {
    const float* loc_preds = (const float*)d_in[0];
    const float* cls_preds = (const float*)d_in[1];
    const float* iou_boxes = (const float*)d_in[2];
    const float* targets   = (const float*)d_in[3];
    float* out = (float*)d_out;

    int*   gcode = (int*)d_ws;
    float* p1    = (float*)d_ws + kCodeFloats;            // 2048*2 floats
    float* p2    = p1 + (size_t)kNB1 * 2;                 // 4096 floats

    dim3 g1(kGrid1, kB), g2(kGrid2, kB);
    iou_kernel<<<g1, kBlock, 0, stream>>>(loc_preds, iou_boxes, targets, gcode, p1);
    focal_kernel<<<g2, kBlock, 0, stream>>>(cls_preds, gcode, p2);
    retina_final<<<1, 1024, 0, stream>>>(p1, p2, out);
}